// Round 1
// baseline (1483.910 us; speedup 1.0000x reference)
//
#include <hip/hip_runtime.h>

// ---------------- problem constants ----------------
#define BB 32
#define TT 720
#define CC 512
#define PHIST 30
#define PFUT 14
#define PLEN 24
#define HID 256
#define NBC (BB*CC)          // 16384 sequences
#define XNELEM (BB*TT*CC)    // 11796480
// K augmented: 256 (h) + 32 (features/embed/const pad) = 288 -> 9 ksteps of 32
#define KSTEPS 9
#define ROWB 640             // LDS bytes per seq row (576 padded to 640 for swizzle)

// ws layout (bytes)
#define OFF_BENC   0u
#define SZ_B       442368u          // 48 tiles * 9 ks * 64 lanes * 16 B
#define OFF_BDEC   442368u
#define OFF_BHEAD  884736u          // 9*64*16 = 9216
#define OFF_INDEC  893952u          // 14*256*4 = 14336
#define OFF_DFEAT  908288u          // 14*9*4 = 504 (padded)
#define OFF_FEAT   908800u          // 30*8*16384*2 = 7864320
#define OFF_LAST   8773120u         // 32*4*512*4 = 262144

typedef short bf16x8 __attribute__((ext_vector_type(8)));
typedef float f32x4 __attribute__((ext_vector_type(4)));

__device__ __forceinline__ unsigned short f2bf(float f){
  unsigned u = __float_as_uint(f);
  u = (u + 0x7fffu + ((u >> 16) & 1u)) >> 16;
  return (unsigned short)u;
}
__device__ __forceinline__ float bf2f(short s){
  return __uint_as_float(((unsigned)(unsigned short)s) << 16);
}
__device__ __forceinline__ float sigm(float x){ return 1.f/(1.f + __expf(-x)); }
__device__ __forceinline__ float tanh_f(float x){ return 2.f/(1.f + __expf(-2.f*x)) - 1.f; }

// ---------------- prep: pack weights into MFMA B-fragment order ----------------
// B tile order per wave w: t6 = gate(r,z,n)*2 + jt ; n = gate*256 + w*32 + jt*16 + (l&15)
// k map: [0,256) Whh ; [256,256+FN) Wih ; k==256+FN const col (biases) ; else 0
__global__ void prep_kernel(
    const float* __restrict__ eWih, const float* __restrict__ eWhh,
    const float* __restrict__ ebih, const float* __restrict__ ebhh,
    const float* __restrict__ dWih, const float* __restrict__ dWhh,
    const float* __restrict__ dbih, const float* __restrict__ dbhh,
    const float* __restrict__ femb, const float* __restrict__ headW,
    const float* __restrict__ headb,
    unsigned short* __restrict__ Benc, unsigned short* __restrict__ Bdec,
    unsigned short* __restrict__ Bhead,
    float* __restrict__ indec, unsigned* __restrict__ dfeat)
{
  const int NE = 48*9*64; // 27648
  int id = blockIdx.x*256 + threadIdx.x;
  if (id < 2*NE){
    bool isenc = id < NE;
    int s = isenc ? id : id - NE;
    int g = s / 576, rem = s % 576, ks = rem / 64, lane = rem % 64;
    int wv = g / 6, t6 = g % 6;
    int n = (t6 >> 1)*256 + wv*32 + (t6 & 1)*16 + (lane & 15);
    int kb = ks*32 + (lane >> 4)*8;
    unsigned short* outp = (isenc ? Benc : Bdec) + (size_t)s*8;
    const float* Whh = isenc ? eWhh : dWhh;
    const float* Wih = isenc ? eWih : dWih;
    const float* bih = isenc ? ebih : dbih;
    const float* bhh = isenc ? ebhh : dbhh;
    const int FN = isenc ? 7 : 16;
    const int KC = 256 + FN;
    for (int e = 0; e < 8; ++e){
      int k = kb + e;
      float v;
      if (k < 256)      v = Whh[n*256 + k];
      else if (k < KC)  v = (n < 512) ? Wih[n*FN + (k - 256)] : 0.f;
      else if (k == KC) v = (n < 512) ? (bih[n] + bhh[n]) : bhh[n];
      else              v = 0.f;
      outp[e] = f2bf(v);
    }
  } else if (id < 2*NE + 576){
    int s = id - 2*NE;
    int ks = s / 64, lane = s % 64;
    int o = lane & 15, kb = ks*32 + (lane >> 4)*8;
    unsigned short* outp = Bhead + (size_t)s*8;
    for (int e = 0; e < 8; ++e){
      int k = kb + e;
      float v = 0.f;
      if (o < 4){
        if (k < 256)       v = headW[o*256 + k];
        else if (k == 272) v = headb[o];
      }
      outp[e] = f2bf(v);
    }
  } else if (id < 2*NE + 576 + PFUT*256){
    int s2 = id - (2*NE + 576);
    int st = s2 >> 8, j = s2 & 255;
    float v = dbih[512 + j];
    for (int f = 0; f < 16; ++f) v = fmaf(femb[st*16 + f], dWih[(512 + j)*16 + f], v);
    indec[s2] = v;
  } else if (id < 2*NE + 576 + PFUT*256 + PFUT*9){
    int s2 = id - (2*NE + 576 + PFUT*256);
    int st = s2 / 9, d = s2 % 9;
    unsigned v;
    if (d < 8) v = (unsigned)f2bf(femb[st*16 + 2*d]) | ((unsigned)f2bf(femb[st*16 + 2*d + 1]) << 16);
    else       v = (unsigned)f2bf(1.0f);
    dfeat[s2] = v;
  }
}

// ---------------- stage A: SWT + stats + features + x_norm ----------------
__global__ __launch_bounds__(64,1) void stage_a_kernel(
    const float* __restrict__ x, float* __restrict__ xnorm,
    unsigned short* __restrict__ feat2, float* __restrict__ last_g)
{
  const int bc = blockIdx.x*64 + threadIdx.x;
  const int b = bc >> 9, c = bc & 511;
  const float* xp = x + (size_t)b*TT*CC + c;
  float* op = xnorm + (size_t)b*TT*CC + c;
  float gsum = 0.f, gss = 0.f;
  float lastv[4] = {0,0,0,0};
  const float inv24 = 1.f/24.f, inv23 = 1.f/23.f;

  for (int p = 0; p < PHIST; ++p){
    const int t0 = p*PLEN;
    float xl[31];
#pragma unroll
    for (int i = 0; i < 31; ++i){
      int t = t0 - 4 + i;
      t = (t < 0) ? -t : ((t >= TT) ? (2*TT - 2 - t) : t);
      xl[i] = xp[(size_t)t*CC];
    }
    float a1l[30];
#pragma unroll
    for (int j = 0; j < 30; ++j) a1l[j] = 0.5f*(xl[j] + xl[j+1]);
    if (p == 0){ a1l[2] = a1l[4]; a1l[1] = a1l[5]; a1l[0] = a1l[6]; }
    if (p == PHIST-1){ a1l[27] = a1l[25]; a1l[28] = a1l[24]; a1l[29] = a1l[23]; }
    float a2l[28];
#pragma unroll
    for (int m = 0; m < 28; ++m) a2l[m] = 0.5f*(a1l[m] + a1l[m+2]);
    if (p == 0){ a2l[1] = a2l[3]; a2l[0] = a2l[4]; }
    if (p == PHIST-1){ a2l[26] = a2l[24]; a2l[27] = a2l[23]; }
    float a3l[24], d1l[24], d2l[24], d3l[24];
    float sL=0, sL2=0, s2=0, s22=0, s3=0, s32=0, sH2=0;
#pragma unroll
    for (int n = 0; n < 24; ++n){
      float a3 = 0.5f*(a2l[n] + a2l[n+4]);
      float d1 = xl[n+4] - a1l[n+3];
      float d2 = a1l[n+3] - a2l[n+2];
      float d3 = a2l[n+2] - a3;
      a3l[n]=a3; d1l[n]=d1; d2l[n]=d2; d3l[n]=d3;
      sL += a3; sL2 += a3*a3;
      s2 += d2; s22 += d2*d2;
      s3 += d3; s32 += d3*d3;
      sH2 += d1*d1;
      gsum += a3; gss += a3*a3;
    }
    float mu   = sL*inv24;
    float sigL = fmaxf(sqrtf(fmaxf((sL2 - sL*sL*inv24)*inv23, 0.f)), 1e-3f);
    float sig2 = fmaxf(sqrtf(fmaxf((s22 - s2*s2*inv24)*inv23, 0.f)), 1e-3f);
    float sig3 = fmaxf(sqrtf(fmaxf((s32 - s3*s3*inv24)*inv23, 0.f)), 1e-3f);
    float EL = sL2*inv24, E2 = s22*inv24, E3 = s32*inv24, EH = sH2*inv24;
    float rho = EH / (EL + EH + E2 + E3 + 1e-6f);
    float lsl = __logf(sigL), ls2 = __logf(sig2), ls3 = __logf(sig3);
    size_t fb = ((size_t)p*8)*NBC + bc;
    feat2[fb + 0*NBC] = f2bf(mu);
    feat2[fb + 1*NBC] = f2bf(lsl);
    feat2[fb + 2*NBC] = f2bf(ls2);
    feat2[fb + 3*NBC] = f2bf(ls3);
    feat2[fb + 4*NBC] = f2bf(rho);
    if (p == PHIST-1){ lastv[0]=mu; lastv[1]=lsl; lastv[2]=ls2; lastv[3]=ls3; }
    float iL = 1.f/sigL, i2 = 1.f/sig2, i3 = 1.f/sig3;
#pragma unroll
    for (int n = 0; n < 24; ++n){
      float v = (a3l[n]-mu)*iL + d1l[n] + d2l[n]*i2 + d3l[n]*i3;
      op[(size_t)(t0+n)*CC] = v;
    }
  }
  float mug  = gsum*(1.f/720.f);
  float sigg = fmaxf(sqrtf(fmaxf((gss - gsum*gsum*(1.f/720.f))*(1.f/719.f), 0.f)), 1e-3f);
  unsigned short f5 = f2bf(mug), f6 = f2bf(__logf(sigg)), f7 = f2bf(1.0f);
  for (int p = 0; p < PHIST; ++p){
    size_t fb = ((size_t)p*8)*NBC + bc;
    feat2[fb + 5*NBC] = f5;
    feat2[fb + 6*NBC] = f6;
    feat2[fb + 7*NBC] = f7;
  }
#pragma unroll
  for (int o = 0; o < 4; ++o) last_g[((size_t)b*4 + o)*CC + c] = lastv[o];
}

// ---------------- GRU: encoder 30 + decoder 14 + fused head ----------------
// 256 blocks x 512 threads; 64 sequences/block; h fp32 in registers,
// bf16 copy in XOR-swizzled LDS [64][640B] for A-fragments (K=288 aug).
__global__ __launch_bounds__(512,2) void gru_kernel(
    const bf16x8* __restrict__ Benc, const bf16x8* __restrict__ Bdec,
    const bf16x8* __restrict__ Bhead,
    const float* __restrict__ indec,        // [14][256] decoder i_n
    const unsigned* __restrict__ dfeat,     // [14][9] packed dec A-aug dwords
    const unsigned short* __restrict__ feat2, // [30][8][16384] bf16
    const float* __restrict__ last_g,       // [32][4][512]
    const float* __restrict__ eWih, const float* __restrict__ ebih,
    float* __restrict__ pred)               // [32][14][4][512]
{
  __shared__ unsigned char Ab[64*ROWB];
  const int tid = threadIdx.x;
  const int w = tid >> 6, l = tid & 63, lr = l & 15, lg = l >> 4;
  const int bc0 = blockIdx.x * 64;
  const int b = bc0 >> 9, c0 = bc0 & 511;

  for (int i = tid; i < 64*ROWB/4; i += 512) ((unsigned*)Ab)[i] = 0u;

  // encoder i_n weights for this lane's two j-columns
  float WihN[2][7], bihN[2];
#pragma unroll
  for (int jt = 0; jt < 2; ++jt){
    int n = 512 + w*32 + jt*16 + lr;
#pragma unroll
    for (int f = 0; f < 7; ++f) WihN[jt][f] = eWih[n*7 + f];
    bihN[jt] = ebih[n];
  }
  float hm[4][2][4];
#pragma unroll
  for (int m=0;m<4;m++)
#pragma unroll
    for (int jt=0;jt<2;jt++)
#pragma unroll
      for (int r=0;r<4;r++) hm[m][jt][r] = 0.f;

  __syncthreads();
  { // stage encoder features for step 0
    int seq = tid & 63, f = tid >> 6;
    unsigned short v = feat2[((size_t)0*8 + f)*NBC + bc0 + seq];
    *(unsigned short*)(Ab + seq*ROWB + ((512 + f*2) ^ ((seq & 7) << 4))) = v;
  }
  __syncthreads();

  for (int step = 0; step < PHIST + PFUT; ++step){
    const bool enc = step < PHIST;
    const bf16x8* Bm = enc ? Benc : Bdec;
    f32x4 acc[6][4];
#pragma unroll
    for (int t=0;t<6;t++)
#pragma unroll
      for (int m=0;m<4;m++) acc[t][m] = (f32x4){0.f,0.f,0.f,0.f};

#pragma unroll
    for (int ks = 0; ks < KSTEPS; ++ks){
      bf16x8 af[4];
#pragma unroll
      for (int m = 0; m < 4; ++m){
        int addr = (m*16 + lr)*ROWB + ((ks*64 + lg*16) ^ ((lr & 7) << 4));
        af[m] = *(const bf16x8*)(Ab + addr);
      }
#pragma unroll
      for (int t = 0; t < 6; ++t){
        bf16x8 bfr = Bm[((size_t)(w*6 + t)*KSTEPS + ks)*64 + l];
#pragma unroll
        for (int m = 0; m < 4; ++m)
          acc[t][m] = __builtin_amdgcn_mfma_f32_16x16x32_bf16(af[m], bfr, acc[t][m], 0, 0, 0);
      }
    }

    // epilogue: gate nonlinearity + state update (h stays fp32 in regs)
    float inj[2] = {0.f, 0.f};
    if (!enc){
      int s = step - PHIST;
#pragma unroll
      for (int jt=0;jt<2;jt++) inj[jt] = indec[s*256 + w*32 + jt*16 + lr];
    }
#pragma unroll
    for (int m = 0; m < 4; ++m){
      bf16x8 fts[4];
      if (enc){
#pragma unroll
        for (int r = 0; r < 4; ++r){
          int seq = m*16 + lg*4 + r;
          fts[r] = *(const bf16x8*)(Ab + seq*ROWB + (512 ^ ((seq & 7) << 4)));
        }
      }
#pragma unroll
      for (int jt = 0; jt < 2; ++jt){
#pragma unroll
        for (int r = 0; r < 4; ++r){
          float rg = sigm(acc[jt][m][r]);
          float zg = sigm(acc[2+jt][m][r]);
          float hn = acc[4+jt][m][r];
          float in_;
          if (enc){
            in_ = bihN[jt];
#pragma unroll
            for (int f = 0; f < 7; ++f) in_ = fmaf(bf2f(fts[r][f]), WihN[jt][f], in_);
          } else {
            in_ = inj[jt];
          }
          float ng = tanh_f(fmaf(rg, hn, in_));
          hm[m][jt][r] = fmaf(zg, hm[m][jt][r] - ng, ng); // (1-z)n + z h
        }
      }
    }
    __syncthreads();

    // write h (bf16, swizzled) + stage next step's input section
#pragma unroll
    for (int m = 0; m < 4; ++m)
#pragma unroll
      for (int jt = 0; jt < 2; ++jt)
#pragma unroll
        for (int r = 0; r < 4; ++r){
          int seq = m*16 + lg*4 + r;
          int koff = (w*32 + jt*16 + lr)*2;
          *(unsigned short*)(Ab + seq*ROWB + (koff ^ ((seq & 7) << 4))) = f2bf(hm[m][jt][r]);
        }
    if (step < PHIST-1){
      int p = step + 1;
      int seq = tid & 63, f = tid >> 6;
      unsigned short v = feat2[((size_t)p*8 + f)*NBC + bc0 + seq];
      *(unsigned short*)(Ab + seq*ROWB + ((512 + f*2) ^ ((seq & 7) << 4))) = v;
    } else if (step < PHIST + PFUT - 1){
      int s = step - (PHIST-1);
      int seq = tid & 63;
      for (int d = tid >> 6; d < 9; d += 8){
        unsigned v = dfeat[s*9 + d];
        *(unsigned*)(Ab + seq*ROWB + ((512 + d*4) ^ ((seq & 7) << 4))) = v;
      }
    }
    __syncthreads();

    // decoder head: delta = h @ headW^T + headb (+last) via one MFMA tile
    if (!enc && w < 4){
      int s = step - PHIST;
      f32x4 ah = (f32x4){0.f,0.f,0.f,0.f};
#pragma unroll
      for (int ks = 0; ks < KSTEPS; ++ks){
        int addr = (w*16 + lr)*ROWB + ((ks*64 + lg*16) ^ ((lr & 7) << 4));
        bf16x8 af = *(const bf16x8*)(Ab + addr);
        ah = __builtin_amdgcn_mfma_f32_16x16x32_bf16(af, Bhead[(size_t)ks*64 + l], ah, 0, 0, 0);
      }
      if (lr < 4){
#pragma unroll
        for (int r = 0; r < 4; ++r){
          int seq = w*16 + lg*4 + r;
          int c = c0 + seq;
          float val = ah[r] + last_g[((size_t)b*4 + lr)*CC + c];
          pred[(((size_t)b*PFUT + s)*4 + lr)*CC + c] = val;
        }
      }
    }
  }
}

extern "C" void kernel_launch(void* const* d_in, const int* in_sizes, int n_in,
                              void* d_out, int out_size, void* d_ws, size_t ws_size,
                              hipStream_t stream)
{
  const float* x     = (const float*)d_in[0];
  const float* eWih  = (const float*)d_in[1];
  const float* eWhh  = (const float*)d_in[2];
  const float* ebih  = (const float*)d_in[3];
  const float* ebhh  = (const float*)d_in[4];
  const float* dWih  = (const float*)d_in[5];
  const float* dWhh  = (const float*)d_in[6];
  const float* dbih  = (const float*)d_in[7];
  const float* dbhh  = (const float*)d_in[8];
  const float* femb  = (const float*)d_in[9];
  const float* headW = (const float*)d_in[10];
  const float* headb = (const float*)d_in[11];

  char* ws = (char*)d_ws;
  unsigned short* BencU = (unsigned short*)(ws + OFF_BENC);
  unsigned short* BdecU = (unsigned short*)(ws + OFF_BDEC);
  unsigned short* BheadU= (unsigned short*)(ws + OFF_BHEAD);
  float* indec          = (float*)(ws + OFF_INDEC);
  unsigned* dfeat       = (unsigned*)(ws + OFF_DFEAT);
  unsigned short* feat2 = (unsigned short*)(ws + OFF_FEAT);
  float* last_g         = (float*)(ws + OFF_LAST);

  float* xnorm = (float*)d_out;
  float* pred  = (float*)d_out + (size_t)XNELEM;

  prep_kernel<<<233, 256, 0, stream>>>(eWih, eWhh, ebih, ebhh,
      dWih, dWhh, dbih, dbhh, femb, headW, headb,
      BencU, BdecU, BheadU, indec, dfeat);
  stage_a_kernel<<<256, 64, 0, stream>>>(x, xnorm, feat2, last_g);
  gru_kernel<<<256, 512, 0, stream>>>(
      (const bf16x8*)BencU, (const bf16x8*)BdecU, (const bf16x8*)BheadU,
      indec, dfeat, feat2, last_g, eWih, ebih, pred);
}

// Round 2
// 552.378 us; speedup vs baseline: 2.6864x; 2.6864x over previous
//
#include <hip/hip_runtime.h>

// ---------------- problem constants ----------------
#define BB 32
#define TT 720
#define CC 512
#define PHIST 30
#define PFUT 14
#define PLEN 24
#define HID 256
#define NBC (BB*CC)          // 16384 sequences
#define XNELEM (BB*TT*CC)    // 11796480
// K augmented: 256 (h, permuted) + 32 (features/embed/const pad) = 288 -> 9 ksteps of 32
#define KSTEPS 9
#define ROWB 640             // LDS bytes per seq row (576 padded to 640 for swizzle)

// ws layout (bytes)
#define OFF_BENC   0u           // 48 tiles * 9 ks * 64 lanes * 16 B = 442368
#define OFF_BDEC   442368u
#define OFF_BHEAD  884736u      // 9*64*16 = 9216
#define OFF_BNIN   893952u      // 2 * 8w * 2jt * 64 lanes * 16 B = 32768 (enc, dec)
#define OFF_DFEAT  926720u      // 14*9*4 = 504 (padded 512)
#define OFF_FEAT   927232u      // 30*8*16384*2 = 7864320
#define OFF_LAST   8791552u     // 32*4*512*4 = 262144

typedef short bf16x8 __attribute__((ext_vector_type(8)));
typedef float f32x4 __attribute__((ext_vector_type(4)));

__device__ __forceinline__ unsigned short f2bf(float f){
  unsigned u = __float_as_uint(f);
  u = (u + 0x7fffu + ((u >> 16) & 1u)) >> 16;
  return (unsigned short)u;
}
__device__ __forceinline__ float bf2f(short s){
  return __uint_as_float(((unsigned)(unsigned short)s) << 16);
}
__device__ __forceinline__ float sigm(float x){ return 1.f/(1.f + __expf(-x)); }
__device__ __forceinline__ float tanh_f(float x){ return 2.f/(1.f + __expf(-2.f*x)) - 1.f; }

// h-column K-permutation: k = w*32 + lr*2 + jt  <->  n = w*32 + jt*16 + lr
__device__ __forceinline__ int nh_of_k(int k){
  return (k & 0xE0) | ((k & 1) << 4) | ((k >> 1) & 15);
}

// ---------------- prep: pack weights into MFMA B-fragment order ----------------
__global__ void prep_kernel(
    const float* __restrict__ eWih, const float* __restrict__ eWhh,
    const float* __restrict__ ebih, const float* __restrict__ ebhh,
    const float* __restrict__ dWih, const float* __restrict__ dWhh,
    const float* __restrict__ dbih, const float* __restrict__ dbhh,
    const float* __restrict__ femb, const float* __restrict__ headW,
    const float* __restrict__ headb,
    unsigned short* __restrict__ Benc, unsigned short* __restrict__ Bdec,
    unsigned short* __restrict__ Bhead, unsigned short* __restrict__ Bnin,
    unsigned* __restrict__ dfeat)
{
  const int NE = 48*9*64; // 27648
  int id = blockIdx.x*256 + threadIdx.x;
  if (id < 2*NE){
    bool isenc = id < NE;
    int s = isenc ? id : id - NE;
    int g = s / 576, rem = s % 576, ks = rem / 64, lane = rem % 64;
    int wv = g / 6, t6 = g % 6;
    int n = (t6 >> 1)*256 + wv*32 + (t6 & 1)*16 + (lane & 15);
    int kb = ks*32 + (lane >> 4)*8;
    unsigned short* outp = (isenc ? Benc : Bdec) + (size_t)s*8;
    const float* Whh = isenc ? eWhh : dWhh;
    const float* Wih = isenc ? eWih : dWih;
    const float* bih = isenc ? ebih : dbih;
    const float* bhh = isenc ? ebhh : dbhh;
    const int FN = isenc ? 7 : 16;
    const int KC = 256 + FN;
    for (int e = 0; e < 8; ++e){
      int k = kb + e;
      float v;
      if (k < 256)            v = Whh[n*256 + nh_of_k(k)];
      else if (n < 512){      // r,z gates: input part + fused bias column
        if (k < KC)           v = Wih[n*FN + (k - 256)];
        else if (k == KC)     v = bih[n] + bhh[n];
        else                  v = 0.f;
      } else {                // n gate: only hidden bias (input part in Bnin)
        v = (k == KC) ? bhh[n] : 0.f;
      }
      outp[e] = f2bf(v);
    }
  } else if (id < 2*NE + 576){
    int s = id - 2*NE;
    int ks = s / 64, lane = s % 64;
    int o = lane & 15, kb = ks*32 + (lane >> 4)*8;
    unsigned short* outp = Bhead + (size_t)s*8;
    for (int e = 0; e < 8; ++e){
      int k = kb + e;
      float v = 0.f;
      if (o < 4){
        if (k < 256)       v = headW[o*256 + nh_of_k(k)];
        else if (k == 272) v = headb[o];
      }
      outp[e] = f2bf(v);
    }
  } else if (id < 2*NE + 576 + 2048){
    // Bnin: i_n input-part tiles, [enc/dec][w][jt][lane] frags, K = aug rows only
    int s3 = id - (2*NE + 576);
    int ed = s3 >> 10, rem = s3 & 1023;
    int wv = rem >> 7, jt = (rem >> 6) & 1, lane = rem & 63;
    int n = 512 + wv*32 + jt*16 + (lane & 15);
    unsigned short* outp = Bnin + (size_t)ed*8192 + (size_t)(((wv*2 + jt)*64) + lane)*8;
    const int FN = ed ? 16 : 7;
    const float* Wih = ed ? dWih : eWih;
    const float* bih = ed ? dbih : ebih;
    for (int e = 0; e < 8; ++e){
      int kk = (lane >> 4)*8 + e;
      float v;
      if (kk < FN)       v = Wih[n*FN + kk];
      else if (kk == FN) v = bih[n];
      else               v = 0.f;
      outp[e] = f2bf(v);
    }
  } else if (id < 2*NE + 576 + 2048 + PFUT*9){
    int s2 = id - (2*NE + 576 + 2048);
    int st = s2 / 9, d = s2 % 9;
    unsigned v;
    if (d < 8) v = (unsigned)f2bf(femb[st*16 + 2*d]) | ((unsigned)f2bf(femb[st*16 + 2*d + 1]) << 16);
    else       v = (unsigned)f2bf(1.0f);
    dfeat[s2] = v;
  }
}

// ---------------- stage A: SWT + stats + features + x_norm ----------------
__global__ __launch_bounds__(64,1) void stage_a_kernel(
    const float* __restrict__ x, float* __restrict__ xnorm,
    unsigned short* __restrict__ feat2, float* __restrict__ last_g)
{
  const int bc = blockIdx.x*64 + threadIdx.x;
  const int b = bc >> 9, c = bc & 511;
  const float* xp = x + (size_t)b*TT*CC + c;
  float* op = xnorm + (size_t)b*TT*CC + c;
  float gsum = 0.f, gss = 0.f;
  float lastv[4] = {0,0,0,0};
  const float inv24 = 1.f/24.f, inv23 = 1.f/23.f;

  for (int p = 0; p < PHIST; ++p){
    const int t0 = p*PLEN;
    float xl[31];
#pragma unroll
    for (int i = 0; i < 31; ++i){
      int t = t0 - 4 + i;
      t = (t < 0) ? -t : ((t >= TT) ? (2*TT - 2 - t) : t);
      xl[i] = xp[(size_t)t*CC];
    }
    float a1l[30];
#pragma unroll
    for (int j = 0; j < 30; ++j) a1l[j] = 0.5f*(xl[j] + xl[j+1]);
    if (p == 0){ a1l[2] = a1l[4]; a1l[1] = a1l[5]; a1l[0] = a1l[6]; }
    if (p == PHIST-1){ a1l[27] = a1l[25]; a1l[28] = a1l[24]; a1l[29] = a1l[23]; }
    float a2l[28];
#pragma unroll
    for (int m = 0; m < 28; ++m) a2l[m] = 0.5f*(a1l[m] + a1l[m+2]);
    if (p == 0){ a2l[1] = a2l[3]; a2l[0] = a2l[4]; }
    if (p == PHIST-1){ a2l[26] = a2l[24]; a2l[27] = a2l[23]; }
    float a3l[24], d1l[24], d2l[24], d3l[24];
    float sL=0, sL2=0, s2=0, s22=0, s3=0, s32=0, sH2=0;
#pragma unroll
    for (int n = 0; n < 24; ++n){
      float a3 = 0.5f*(a2l[n] + a2l[n+4]);
      float d1 = xl[n+4] - a1l[n+3];
      float d2 = a1l[n+3] - a2l[n+2];
      float d3 = a2l[n+2] - a3;
      a3l[n]=a3; d1l[n]=d1; d2l[n]=d2; d3l[n]=d3;
      sL += a3; sL2 += a3*a3;
      s2 += d2; s22 += d2*d2;
      s3 += d3; s32 += d3*d3;
      sH2 += d1*d1;
      gsum += a3; gss += a3*a3;
    }
    float mu   = sL*inv24;
    float sigL = fmaxf(sqrtf(fmaxf((sL2 - sL*sL*inv24)*inv23, 0.f)), 1e-3f);
    float sig2 = fmaxf(sqrtf(fmaxf((s22 - s2*s2*inv24)*inv23, 0.f)), 1e-3f);
    float sig3 = fmaxf(sqrtf(fmaxf((s32 - s3*s3*inv24)*inv23, 0.f)), 1e-3f);
    float EL = sL2*inv24, E2 = s22*inv24, E3 = s32*inv24, EH = sH2*inv24;
    float rho = EH / (EL + EH + E2 + E3 + 1e-6f);
    float lsl = __logf(sigL), ls2 = __logf(sig2), ls3 = __logf(sig3);
    size_t fb = ((size_t)p*8)*NBC + bc;
    feat2[fb + 0*NBC] = f2bf(mu);
    feat2[fb + 1*NBC] = f2bf(lsl);
    feat2[fb + 2*NBC] = f2bf(ls2);
    feat2[fb + 3*NBC] = f2bf(ls3);
    feat2[fb + 4*NBC] = f2bf(rho);
    if (p == PHIST-1){ lastv[0]=mu; lastv[1]=lsl; lastv[2]=ls2; lastv[3]=ls3; }
    float iL = 1.f/sigL, i2 = 1.f/sig2, i3 = 1.f/sig3;
#pragma unroll
    for (int n = 0; n < 24; ++n){
      float v = (a3l[n]-mu)*iL + d1l[n] + d2l[n]*i2 + d3l[n]*i3;
      op[(size_t)(t0+n)*CC] = v;
    }
  }
  float mug  = gsum*(1.f/720.f);
  float sigg = fmaxf(sqrtf(fmaxf((gss - gsum*gsum*(1.f/720.f))*(1.f/719.f), 0.f)), 1e-3f);
  unsigned short f5 = f2bf(mug), f6 = f2bf(__logf(sigg)), f7 = f2bf(1.0f);
  for (int p = 0; p < PHIST; ++p){
    size_t fb = ((size_t)p*8)*NBC + bc;
    feat2[fb + 5*NBC] = f5;
    feat2[fb + 6*NBC] = f6;
    feat2[fb + 7*NBC] = f7;
  }
#pragma unroll
  for (int o = 0; o < 4; ++o) last_g[((size_t)b*4 + o)*CC + c] = lastv[o];
}

// ---------------- GRU: encoder 30 + decoder 14 + fused head ----------------
// 256 blocks x 512 threads; 64 seqs/block; h packed bf16 in regs; B streamed
// through a 3-slot register pipeline (prefetch distance 2, mod-3 = static).
__global__ __launch_bounds__(512,2) void gru_kernel(
    const bf16x8* __restrict__ Benc, const bf16x8* __restrict__ Bdec,
    const bf16x8* __restrict__ Bhead, const bf16x8* __restrict__ BninP,
    const unsigned* __restrict__ dfeat,       // [14][9] packed dec A-aug dwords
    const unsigned short* __restrict__ feat2, // [30][8][16384] bf16
    const float* __restrict__ last_g,         // [32][4][512]
    float* __restrict__ pred)                 // [32][14][4][512]
{
  __shared__ unsigned char Ab[64*ROWB];
  const int tid = threadIdx.x;
  const int w = tid >> 6, l = tid & 63, lr = l & 15, lg = l >> 4;
  const int bc0 = blockIdx.x * 64;
  const int b = bc0 >> 9, c0 = bc0 & 511;

  for (int i = tid; i < 64*ROWB/4; i += 512) ((unsigned*)Ab)[i] = 0u;

  // per-wave B fragment bases
  const bf16x8* Bwe = Benc + ((size_t)w*6*KSTEPS)*64 + l;
  const bf16x8* Bwd = Bdec + ((size_t)w*6*KSTEPS)*64 + l;

  // i_n input-part tiles (resident; reloaded at decoder start)
  bf16x8 bnin0 = BninP[(size_t)(w*2 + 0)*64 + l];
  bf16x8 bnin1 = BninP[(size_t)(w*2 + 1)*64 + l];

  // packed h state: bf16 pair (jt0 | jt1<<16) per (m, r)
  unsigned hp[4][4];
#pragma unroll
  for (int m=0;m<4;m++)
#pragma unroll
    for (int r=0;r<4;r++) hp[m][r] = 0u;

  // B register pipeline: 3 slots x 6 tiles, prefetch distance 2
  bf16x8 bb[3][6];
#pragma unroll
  for (int t=0;t<6;t++){
    bb[0][t] = Bwe[(t*KSTEPS + 0)*64];
    bb[1][t] = Bwe[(t*KSTEPS + 1)*64];
  }

  __syncthreads();
  { // stage encoder features for step 0
    int seq = tid & 63, f = tid >> 6;
    unsigned short v = feat2[((size_t)0*8 + f)*NBC + bc0 + seq];
    *(unsigned short*)(Ab + seq*ROWB + ((512 + f*2) ^ ((seq & 7) << 4))) = v;
  }
  __syncthreads();

  for (int step = 0; step < PHIST + PFUT; ++step){
    const bool enc = step < PHIST;
    const bf16x8* Bcur = enc ? Bwe : Bwd;
    const bf16x8* Bnxt = (step == PHIST-1) ? Bwd : ((step == PHIST+PFUT-1) ? Bwe : Bcur);
    if (step == PHIST){
      bnin0 = BninP[1024 + (size_t)(w*2 + 0)*64 + l];
      bnin1 = BninP[1024 + (size_t)(w*2 + 1)*64 + l];
    }

    f32x4 acc[6][4];
    f32x4 accin[2][4];
#pragma unroll
    for (int t=0;t<6;t++)
#pragma unroll
      for (int m=0;m<4;m++) acc[t][m] = (f32x4){0.f,0.f,0.f,0.f};
#pragma unroll
    for (int jt=0;jt<2;jt++)
#pragma unroll
      for (int m=0;m<4;m++) accin[jt][m] = (f32x4){0.f,0.f,0.f,0.f};

#pragma unroll
    for (int ks = 0; ks < KSTEPS; ++ks){
      // prefetch ks+2 (next step's ks when wrapping) into slot (ks+2)%3
      {
        const int tks = ks + 2;
        const bf16x8* bp = (tks < KSTEPS) ? Bcur : Bnxt;
        const int rks = (tks < KSTEPS) ? tks : (tks - KSTEPS);
#pragma unroll
        for (int t=0;t<6;t++) bb[tks%3][t] = bp[(t*KSTEPS + rks)*64];
      }
      bf16x8 af[4];
#pragma unroll
      for (int m = 0; m < 4; ++m){
        int addr = (m*16 + lr)*ROWB + ((ks*64 + lg*16) ^ ((lr & 7) << 4));
        af[m] = *(const bf16x8*)(Ab + addr);
      }
#pragma unroll
      for (int t = 0; t < 6; ++t)
#pragma unroll
        for (int m = 0; m < 4; ++m)
          acc[t][m] = __builtin_amdgcn_mfma_f32_16x16x32_bf16(af[m], bb[ks%3][t], acc[t][m], 0, 0, 0);
      if (ks == KSTEPS-1){
#pragma unroll
        for (int m = 0; m < 4; ++m){
          accin[0][m] = __builtin_amdgcn_mfma_f32_16x16x32_bf16(af[m], bnin0, accin[0][m], 0, 0, 0);
          accin[1][m] = __builtin_amdgcn_mfma_f32_16x16x32_bf16(af[m], bnin1, accin[1][m], 0, 0, 0);
        }
      }
    }

    // epilogue: gates + state update (register-only)
#pragma unroll
    for (int m = 0; m < 4; ++m){
#pragma unroll
      for (int r = 0; r < 4; ++r){
        float h0 = bf2f((short)(hp[m][r] & 0xffff));
        float h1 = bf2f((short)(hp[m][r] >> 16));
        float rg0 = sigm(acc[0][m][r]), rg1 = sigm(acc[1][m][r]);
        float zg0 = sigm(acc[2][m][r]), zg1 = sigm(acc[3][m][r]);
        float n0 = tanh_f(fmaf(rg0, acc[4][m][r], accin[0][m][r]));
        float n1 = tanh_f(fmaf(rg1, acc[5][m][r], accin[1][m][r]));
        h0 = fmaf(zg0, h0 - n0, n0);
        h1 = fmaf(zg1, h1 - n1, n1);
        hp[m][r] = (unsigned)f2bf(h0) | ((unsigned)f2bf(h1) << 16);
      }
    }
    __syncthreads();

    // write packed h (one b32 per (m,r)) + stage next step's input section
#pragma unroll
    for (int m = 0; m < 4; ++m)
#pragma unroll
      for (int r = 0; r < 4; ++r){
        int seq = m*16 + lg*4 + r;
        *(unsigned*)(Ab + seq*ROWB + ((w*64 + lr*4) ^ ((seq & 7) << 4))) = hp[m][r];
      }
    if (step < PHIST-1){
      int p = step + 1;
      int seq = tid & 63, f = tid >> 6;
      unsigned short v = feat2[((size_t)p*8 + f)*NBC + bc0 + seq];
      *(unsigned short*)(Ab + seq*ROWB + ((512 + f*2) ^ ((seq & 7) << 4))) = v;
    } else if (step < PHIST + PFUT - 1){
      int s = step - (PHIST-1);
      int seq = tid & 63;
      for (int d = tid >> 6; d < 9; d += 8){
        unsigned v = dfeat[s*9 + d];
        *(unsigned*)(Ab + seq*ROWB + ((512 + d*4) ^ ((seq & 7) << 4))) = v;
      }
    }
    __syncthreads();

    // decoder head: delta = h @ headW^T + headb (+last) via one MFMA tile
    if (!enc && w < 4){
      int s = step - PHIST;
      f32x4 ah = (f32x4){0.f,0.f,0.f,0.f};
#pragma unroll
      for (int ks = 0; ks < KSTEPS; ++ks){
        int addr = (w*16 + lr)*ROWB + ((ks*64 + lg*16) ^ ((lr & 7) << 4));
        bf16x8 af = *(const bf16x8*)(Ab + addr);
        ah = __builtin_amdgcn_mfma_f32_16x16x32_bf16(af, Bhead[(size_t)ks*64 + l], ah, 0, 0, 0);
      }
      if (lr < 4){
#pragma unroll
        for (int r = 0; r < 4; ++r){
          int seq = w*16 + lg*4 + r;
          int c = c0 + seq;
          float val = ah[r] + last_g[((size_t)b*4 + lr)*CC + c];
          pred[(((size_t)b*PFUT + s)*4 + lr)*CC + c] = val;
        }
      }
    }
  }
}

extern "C" void kernel_launch(void* const* d_in, const int* in_sizes, int n_in,
                              void* d_out, int out_size, void* d_ws, size_t ws_size,
                              hipStream_t stream)
{
  const float* x     = (const float*)d_in[0];
  const float* eWih  = (const float*)d_in[1];
  const float* eWhh  = (const float*)d_in[2];
  const float* ebih  = (const float*)d_in[3];
  const float* ebhh  = (const float*)d_in[4];
  const float* dWih  = (const float*)d_in[5];
  const float* dWhh  = (const float*)d_in[6];
  const float* dbih  = (const float*)d_in[7];
  const float* dbhh  = (const float*)d_in[8];
  const float* femb  = (const float*)d_in[9];
  const float* headW = (const float*)d_in[10];
  const float* headb = (const float*)d_in[11];

  char* ws = (char*)d_ws;
  unsigned short* BencU = (unsigned short*)(ws + OFF_BENC);
  unsigned short* BdecU = (unsigned short*)(ws + OFF_BDEC);
  unsigned short* BheadU= (unsigned short*)(ws + OFF_BHEAD);
  unsigned short* BninU = (unsigned short*)(ws + OFF_BNIN);
  unsigned* dfeat       = (unsigned*)(ws + OFF_DFEAT);
  unsigned short* feat2 = (unsigned short*)(ws + OFF_FEAT);
  float* last_g         = (float*)(ws + OFF_LAST);

  float* xnorm = (float*)d_out;
  float* pred  = (float*)d_out + (size_t)XNELEM;

  prep_kernel<<<227, 256, 0, stream>>>(eWih, eWhh, ebih, ebhh,
      dWih, dWhh, dbih, dbhh, femb, headW, headb,
      BencU, BdecU, BheadU, BninU, dfeat);
  stage_a_kernel<<<256, 64, 0, stream>>>(x, xnorm, feat2, last_g);
  gru_kernel<<<256, 512, 0, stream>>>(
      (const bf16x8*)BencU, (const bf16x8*)BdecU, (const bf16x8*)BheadU,
      (const bf16x8*)BninU, dfeat, feat2, last_g, pred);
}